// Round 11
// baseline (421.783 us; speedup 1.0000x reference)
//
#include <hip/hip_runtime.h>
#include <hip/hip_bf16.h>
#include <math.h>

typedef __attribute__((ext_vector_type(8))) short short8;
typedef __attribute__((ext_vector_type(4))) float f32x4;

__device__ inline ushort f2bf(float f) {
    uint u = __builtin_bit_cast(uint, f);
    u += 0x7fffu + ((u >> 16) & 1u);          // round-to-nearest-even
    return (ushort)(u >> 16);
}
__device__ inline float bf2f(ushort h) {
    return __builtin_bit_cast(float, (uint)h << 16);
}

// ================= CSR build: bucket counting-sort, zero global per-node atomics ==========
// Buckets: 256 node ranges of width W = ceil(N/256) (requires W <= 512, N <= 131072).
// Edge packed as src | ((d - bucket_lo) << 17)  (src < 2^17, local idx < 2^9).

#define NB   256
#define CNTB 1024
#define BKE  2048
#define MAXBE 16384

__device__ inline int bucket_of(int d, int W, float recipW) {
    int g = (int)((float)d * recipW);
    if (g > NB - 1) g = NB - 1;
    while (d < g * W) --g;
    while (d >= (g + 1) * W) ++g;
    return g;
}

__global__ __launch_bounds__(256) void bucketcnt_kernel(const int* __restrict__ dst,
                                                        int* __restrict__ bcntpart,
                                                        int E, int W, float recipW) {
    __shared__ int hist[NB];
    int tid = threadIdx.x;
    hist[tid] = 0;
    __syncthreads();
    int per = (E + CNTB - 1) / CNTB;
    int e0 = blockIdx.x * per;
    int e1 = e0 + per; if (e1 > E) e1 = E;
    for (int e = e0 + tid; e < e1; e += 256)
        atomicAdd(&hist[bucket_of(dst[e], W, recipW)], 1);
    __syncthreads();
    bcntpart[blockIdx.x * NB + tid] = hist[tid];
}

__global__ __launch_bounds__(256) void scan256_kernel(const int* __restrict__ bcntpart,
                                                      int* __restrict__ bbase,
                                                      int* __restrict__ cursor256) {
    __shared__ int tot[NB];
    int b = threadIdx.x;
    int s = 0;
    for (int i = 0; i < CNTB; ++i) s += bcntpart[i * NB + b];
    int val = s;
    tot[b] = s;
    __syncthreads();
    for (int off = 1; off < NB; off <<= 1) {
        int t = (b >= off) ? tot[b - off] : 0;
        __syncthreads();
        tot[b] += t;
        __syncthreads();
    }
    int excl = tot[b] - val;
    bbase[b] = excl;
    cursor256[b] = excl;
    if (b == NB - 1) bbase[NB] = tot[NB - 1];
}

__global__ __launch_bounds__(256) void bucket_kernel(const int* __restrict__ src, const int* __restrict__ dst,
                                                     int* __restrict__ cursor256, int* __restrict__ epk,
                                                     int E, int W, float recipW) {
    __shared__ int hist[NB];
    __shared__ int base[NB];
    int tid = threadIdx.x;
    int e0 = blockIdx.x * BKE;
    int e1 = e0 + BKE; if (e1 > E) e1 = E;
    if (e0 >= E) return;
    hist[tid] = 0;
    __syncthreads();
    int myp[8], myg[8], myr[8];
    #pragma unroll
    for (int it = 0; it < 8; ++it) {
        int e = e0 + tid + it * 256;
        myg[it] = -1;
        if (e < e1) {
            int d = dst[e];
            int g = bucket_of(d, W, recipW);
            myp[it] = src[e] | ((d - g * W) << 17);
            myg[it] = g;
            myr[it] = atomicAdd(&hist[g], 1);
        }
    }
    __syncthreads();
    base[tid] = atomicAdd(&cursor256[tid], hist[tid]);
    __syncthreads();
    #pragma unroll
    for (int it = 0; it < 8; ++it)
        if (myg[it] >= 0)
            epk[base[myg[it]] + myr[it]] = myp[it];
}

// one block per bucket: LDS histogram -> scan -> offs/dinv out -> LDS counting-scatter -> csr
__global__ __launch_bounds__(256) void sortcsr_kernel(const int* __restrict__ epk,
                                                      const int* __restrict__ bbase,
                                                      int* __restrict__ csr, int* __restrict__ offs,
                                                      float* __restrict__ dinv, int N, int W, int E) {
    __shared__ int lcnt[512];
    __shared__ int lofs[513];
    __shared__ int tmp[256];
    __shared__ int lcsr[MAXBE];
    int b = blockIdx.x;
    int lo = b * W;
    int nloc = N - lo; if (nloc > W) nloc = W; if (nloc < 0) nloc = 0;
    int eb = bbase[b], ee = bbase[b + 1];
    int tid = threadIdx.x;
    lcnt[2 * tid] = 0; lcnt[2 * tid + 1] = 0;
    __syncthreads();
    for (int e = eb + tid; e < ee; e += 256)
        atomicAdd(&lcnt[epk[e] >> 17], 1);
    __syncthreads();
    // exclusive scan over 512 entries (2 per thread)
    int a0 = lcnt[2 * tid], a1 = lcnt[2 * tid + 1];
    int psum = a0 + a1;
    tmp[tid] = psum;
    __syncthreads();
    for (int off = 1; off < 256; off <<= 1) {
        int t = (tid >= off) ? tmp[tid - off] : 0;
        __syncthreads();
        tmp[tid] += t;
        __syncthreads();
    }
    int excl = tmp[tid] - psum;
    lofs[2 * tid] = excl;
    lofs[2 * tid + 1] = excl + a0;
    lcnt[2 * tid] = excl;          // reset as cursor
    lcnt[2 * tid + 1] = excl + a0;
    if (tid == 255) lofs[512] = tmp[255];
    __syncthreads();
    // emit offs + dinv
    for (int t = tid; t < nloc; t += 256) {
        offs[lo + t] = eb + lofs[t];
        int deg = lofs[t + 1] - lofs[t];
        dinv[lo + t] = rsqrtf((float)(deg + 1));
    }
    if (b == NB - 1 && tid == 0) offs[N] = E;
    // counting scatter into LDS, then sequential stream-out
    for (int e = eb + tid; e < ee; e += 256) {
        int p = epk[e];
        int pos = atomicAdd(&lcnt[p >> 17], 1);
        int sv = p & 0x1FFFF;
        if (pos < MAXBE) lcsr[pos] = sv;
        else csr[eb + pos] = sv;       // statistically-unreachable overflow fallback
    }
    __syncthreads();
    int ne = ee - eb; if (ne > MAXBE) ne = MAXBE;
    for (int e = tid; e < ne; e += 256) csr[eb + e] = lcsr[e];
}

// ---------------- weight prep: Wt[128][512] bf16 (transposed), bcat[128], W3s[32*40], b3s[40] ----

__global__ __launch_bounds__(256) void prep_kernel(const float* __restrict__ W1a, const float* __restrict__ W1b,
                                                   const float* __restrict__ W2a, const float* __restrict__ W2b,
                                                   const float* __restrict__ b1a, const float* __restrict__ b1b,
                                                   const float* __restrict__ b2a, const float* __restrict__ b2b,
                                                   const float* __restrict__ W3a, const float* __restrict__ W3b,
                                                   const float* __restrict__ b3a, const float* __restrict__ b3b,
                                                   ushort* __restrict__ Wt, float* __restrict__ bcat,
                                                   float* __restrict__ W3s, float* __restrict__ b3s) {
    int idx = blockIdx.x * 256 + threadIdx.x;
    if (idx < 128 * 512) {
        int c = idx >> 9, k = idx & 511;   // Wt[c][k] = Wcat[k][c]
        const float* W = (c < 32) ? W1a : (c < 64) ? W1b : (c < 96) ? W2a : W2b;
        Wt[idx] = f2bf(W[k * 32 + (c & 31)]);
    }
    if (idx < 1280) W3s[idx] = W3a[idx] + W3b[idx];
    if (idx < 128) {
        const float* b = (idx < 32) ? b1a : (idx < 64) ? b1b : (idx < 96) ? b2a : b2b;
        bcat[idx] = b[idx & 31];
    }
    if (idx < 40) b3s[idx] = b3a[idx] + b3b[idx];
}

// ---------------- MFMA GEMM: HWp[N][128] = bf16( (X@Wcat)[r][c] * dinv[r] ) ----------------
// 64 rows x 128 cols, 4 waves. BK=64. Alds double-buffered (2x8KB), Blds single (16KB,
// decoupled by b4 register prefetch) -> 32KB LDS -> 5 blocks/CU (20 waves/CU).
// Epilogue stages the 64x128 bf16 tile in LDS (reusing Alds) -> full-line streaming writes.

#define GBM 64

__global__ __launch_bounds__(256) void gemm_mfma(const float* __restrict__ X,
                                                 const ushort* __restrict__ Wt,
                                                 const float* __restrict__ dinv,
                                                 ushort* __restrict__ HWp, int N) {
    __shared__ ushort Alds[2][64 * 64];    // 16KB total; reused as epilogue staging
    __shared__ ushort Blds[128 * 64];      // 16KB
    const int tid = threadIdx.x;
    const int lane = tid & 63;
    const int wave = tid >> 6;
    const int rQ = lane & 15, g = lane >> 4;
    const int swz = rQ & 7;
    const int rowBase = blockIdx.x * GBM;

    const int ar = tid >> 2, aq = tid & 3;
    int arow = rowBase + ar; if (arow > N - 1) arow = N - 1;
    const float* aglob = X + (size_t)arow * 512 + aq * 4;

    const int br = tid >> 1, bh = tid & 1;
    const ushort* bglob = Wt + (size_t)br * 512 + bh * 32;

    float4 a4[4];
    uint4 b4[4];
    f32x4 acc[4][2] = {};

#define LOAD_REGS(k0)                                                       \
    {                                                                       \
        _Pragma("unroll")                                                   \
        for (int i = 0; i < 4; ++i) a4[i] = *(const float4*)(aglob + (k0) + i * 16); \
        _Pragma("unroll")                                                   \
        for (int i = 0; i < 4; ++i) b4[i] = *(const uint4*)(bglob + (k0) + i * 8);   \
    }

#define WRITE_LDS(buf)                                                      \
    {                                                                       \
        _Pragma("unroll")                                                   \
        for (int i = 0; i < 4; ++i) {                                       \
            int c = i * 2 + (aq >> 1);                                      \
            ushort4 u; u.x = f2bf(a4[i].x); u.y = f2bf(a4[i].y);            \
            u.z = f2bf(a4[i].z); u.w = f2bf(a4[i].w);                       \
            *(ushort4*)(&Alds[buf][ar * 64 + ((c ^ (ar & 7)) << 3) + (aq & 1) * 4]) = u; \
        }                                                                   \
        ushort* bp = &Blds[br * 64];                                        \
        _Pragma("unroll")                                                   \
        for (int i = 0; i < 4; ++i) {                                       \
            int c = bh * 4 + i;                                             \
            *(uint4*)(bp + ((c ^ (br & 7)) << 3)) = b4[i];                  \
        }                                                                   \
    }

#define COMPUTE(buf)                                                        \
    {                                                                       \
        short8 bf[2][2];                                                    \
        _Pragma("unroll")                                                   \
        for (int ct2 = 0; ct2 < 2; ++ct2) {                                 \
            int brow = wave * 32 + ct2 * 16 + rQ;                           \
            _Pragma("unroll")                                               \
            for (int sub = 0; sub < 2; ++sub)                               \
                bf[ct2][sub] = *(const short8*)(&Blds[brow * 64 + (((sub * 4 + g) ^ swz) << 3)]); \
        }                                                                   \
        _Pragma("unroll")                                                   \
        for (int rt = 0; rt < 4; ++rt) {                                    \
            int arw = rt * 16 + rQ;                                         \
            _Pragma("unroll")                                               \
            for (int sub = 0; sub < 2; ++sub) {                             \
                short8 af = *(const short8*)(&Alds[buf][arw * 64 + (((sub * 4 + g) ^ swz) << 3)]); \
                _Pragma("unroll")                                           \
                for (int ct2 = 0; ct2 < 2; ++ct2)                           \
                    acc[rt][ct2] = __builtin_amdgcn_mfma_f32_16x16x32_bf16( \
                        af, bf[ct2][sub], acc[rt][ct2], 0, 0, 0);           \
            }                                                               \
        }                                                                   \
    }

    LOAD_REGS(0);
    WRITE_LDS(0);
    for (int s = 0; s < 8; ++s) {
        __syncthreads();                       // staging for step s visible
        if (s + 1 < 8) LOAD_REGS((s + 1) * 64);  // prefetch flies during compute
        COMPUTE(s & 1);
        if (s + 1 < 8) {
            __syncthreads();                   // all waves done reading Blds/Alds[buf^1]
            WRITE_LDS((s + 1) & 1);
        }
    }

    // epilogue: acc -> LDS (bf16, dinv-scaled) -> full-line streaming write
    __syncthreads();
    ushort* ep = &Alds[0][0];                  // 8192 ushorts = 64 x 128 tile
    #pragma unroll
    for (int rt = 0; rt < 4; ++rt) {
        #pragma unroll
        for (int j = 0; j < 4; ++j) {
            int lr = rt * 16 + g * 4 + j;
            int r = rowBase + lr;
            float dv = (r < N) ? dinv[r] : 0.f;
            #pragma unroll
            for (int ct2 = 0; ct2 < 2; ++ct2) {
                int c = wave * 32 + ct2 * 16 + rQ;
                ep[lr * 128 + c] = f2bf(acc[rt][ct2][j] * dv);
            }
        }
    }
    __syncthreads();
    {
        int lr = tid >> 2, q = tid & 3;        // row, 64B quarter
        int r = rowBase + lr;
        if (r < N) {
            uint4* dstp = (uint4*)(HWp + (size_t)r * 128 + q * 32);
            const uint4* srcp = (const uint4*)(ep + lr * 128 + q * 32);
            #pragma unroll
            for (int i = 0; i < 4; ++i) dstp[i] = srcp[i];
        }
    }
#undef LOAD_REGS
#undef WRITE_LDS
#undef COMPUTE
}

// ---------------- aggregation 128 (bf16 gather, unroll-4 MLP) + fused relu/bias/block-sum ----------

__global__ __launch_bounds__(256) void agg128(const ushort* __restrict__ HWp, const float* __restrict__ dinv,
                                              const int* __restrict__ offs, const int* __restrict__ csr,
                                              const float* __restrict__ bcat, ushort* __restrict__ xsp, int N) {
    int t = blockIdx.x * 256 + threadIdx.x;
    int node = t >> 5, c = t & 31;      // lane c holds features 4c..4c+3
    if (node >= N) return;
    const ushort4* H = (const ushort4*)HWp;
    ushort4 h = H[(size_t)node * 32 + c];
    float a0 = bf2f(h.x), a1 = bf2f(h.y), a2 = bf2f(h.z), a3 = bf2f(h.w);
    int j = offs[node];
    int e1 = offs[node + 1];
    int jend = j + ((e1 - j) & ~3);
    for (; j < jend; j += 4) {
        int s0 = csr[j], s1 = csr[j + 1], s2 = csr[j + 2], s3 = csr[j + 3];
        ushort4 v0 = H[(size_t)s0 * 32 + c];
        ushort4 v1 = H[(size_t)s1 * 32 + c];
        ushort4 v2 = H[(size_t)s2 * 32 + c];
        ushort4 v3 = H[(size_t)s3 * 32 + c];
        a0 += bf2f(v0.x) + bf2f(v1.x) + bf2f(v2.x) + bf2f(v3.x);
        a1 += bf2f(v0.y) + bf2f(v1.y) + bf2f(v2.y) + bf2f(v3.y);
        a2 += bf2f(v0.z) + bf2f(v1.z) + bf2f(v2.z) + bf2f(v3.z);
        a3 += bf2f(v0.w) + bf2f(v1.w) + bf2f(v2.w) + bf2f(v3.w);
    }
    for (; j < e1; ++j) {
        int s = csr[j];
        ushort4 v = H[(size_t)s * 32 + c];
        a0 += bf2f(v.x); a1 += bf2f(v.y); a2 += bf2f(v.z); a3 += bf2f(v.w);
    }
    float di = dinv[node];
    float4 b = *(const float4*)(bcat + c * 4);
    float r0 = fmaxf(di * a0 + b.x, 0.f);
    float r1 = fmaxf(di * a1 + b.y, 0.f);
    float r2 = fmaxf(di * a2 + b.z, 0.f);
    float r3 = fmaxf(di * a3 + b.w, 0.f);
    r0 += __shfl_xor(r0, 8);  r1 += __shfl_xor(r1, 8);  r2 += __shfl_xor(r2, 8);  r3 += __shfl_xor(r3, 8);
    r0 += __shfl_xor(r0, 16); r1 += __shfl_xor(r1, 16); r2 += __shfl_xor(r2, 16); r3 += __shfl_xor(r3, 16);
    if ((c & 24) == 0) {
        ushort4 o;
        o.x = f2bf(r0 * di); o.y = f2bf(r1 * di); o.z = f2bf(r2 * di); o.w = f2bf(r3 * di);
        *(ushort4*)(xsp + (size_t)node * 32 + c * 4) = o;
    }
}

// ---------------- aggregation 32 (bf16 gather, unroll-4 MLP) -> axs f32 ----------------

__global__ __launch_bounds__(256) void agg32(const ushort* __restrict__ xsp, const float* __restrict__ dinv,
                                             const int* __restrict__ offs, const int* __restrict__ csr,
                                             float* __restrict__ axs, int N) {
    int t = blockIdx.x * 256 + threadIdx.x;
    int node = t >> 2, l = t & 3;
    if (node >= N) return;
    const short8* Xr = (const short8*)xsp;   // [N][4] chunks of 8 bf16
    short8 h = Xr[(size_t)node * 4 + l];
    float a[8];
    #pragma unroll
    for (int i = 0; i < 8; ++i) a[i] = bf2f((ushort)h[i]);
    int j = offs[node];
    int e1 = offs[node + 1];
    int jend = j + ((e1 - j) & ~3);
    for (; j < jend; j += 4) {
        int s0 = csr[j], s1 = csr[j + 1], s2 = csr[j + 2], s3 = csr[j + 3];
        short8 v0 = Xr[(size_t)s0 * 4 + l];
        short8 v1 = Xr[(size_t)s1 * 4 + l];
        short8 v2 = Xr[(size_t)s2 * 4 + l];
        short8 v3 = Xr[(size_t)s3 * 4 + l];
        #pragma unroll
        for (int i = 0; i < 8; ++i)
            a[i] += bf2f((ushort)v0[i]) + bf2f((ushort)v1[i]) + bf2f((ushort)v2[i]) + bf2f((ushort)v3[i]);
    }
    for (; j < e1; ++j) {
        int s = csr[j];
        short8 v = Xr[(size_t)s * 4 + l];
        #pragma unroll
        for (int i = 0; i < 8; ++i) a[i] += bf2f((ushort)v[i]);
    }
    float di = dinv[node];
    float4 o0 = make_float4(a[0] * di, a[1] * di, a[2] * di, a[3] * di);
    float4 o1 = make_float4(a[4] * di, a[5] * di, a[6] * di, a[7] * di);
    float* dst = axs + (size_t)node * 32 + l * 8;
    *(float4*)dst = o0;
    *(float4*)(dst + 4) = o1;
}

// ---------------- final: logits = axs @ W3s + b3s ; log_softmax ----------------

__global__ __launch_bounds__(256) void final_kernel(const float* __restrict__ axs, const float* __restrict__ W3s,
                                                    const float* __restrict__ b3s, float* __restrict__ out, int N) {
    __shared__ float w[32 * 40];
    __shared__ float b[40];
    int tid = threadIdx.x;
    for (int i = tid; i < 1280; i += 256) w[i] = W3s[i];
    if (tid < 40) b[tid] = b3s[tid];
    __syncthreads();
    int i = blockIdx.x * 256 + tid;
    if (i >= N) return;
    float a[32];
    #pragma unroll
    for (int q = 0; q < 8; ++q) {
        float4 v = *(const float4*)(axs + (size_t)i * 32 + q * 4);
        a[q * 4] = v.x; a[q * 4 + 1] = v.y; a[q * 4 + 2] = v.z; a[q * 4 + 3] = v.w;
    }
    float acc[40];
    #pragma unroll
    for (int c = 0; c < 40; ++c) acc[c] = b[c];
    #pragma unroll
    for (int k = 0; k < 32; ++k) {
        float av = a[k];
        #pragma unroll
        for (int c = 0; c < 40; ++c) acc[c] += av * w[k * 40 + c];
    }
    float m = acc[0];
    #pragma unroll
    for (int c = 1; c < 40; ++c) m = fmaxf(m, acc[c]);
    float sum = 0.f;
    #pragma unroll
    for (int c = 0; c < 40; ++c) sum += expf(acc[c] - m);
    float lg = m + logf(sum);
    #pragma unroll
    for (int c = 0; c < 40; ++c) out[(size_t)i * 40 + c] = acc[c] - lg;
}

// ---------------- launch ----------------

extern "C" void kernel_launch(void* const* d_in, const int* in_sizes, int n_in,
                              void* d_out, int out_size, void* d_ws, size_t ws_size,
                              hipStream_t stream) {
    const float* x   = (const float*)d_in[0];
    const int*   ei  = (const int*)d_in[1];
    const float* W1a = (const float*)d_in[2];  const float* b1a = (const float*)d_in[3];
    const float* W1b = (const float*)d_in[4];  const float* b1b = (const float*)d_in[5];
    const float* W2a = (const float*)d_in[6];  const float* b2a = (const float*)d_in[7];
    const float* W2b = (const float*)d_in[8];  const float* b2b = (const float*)d_in[9];
    const float* W3a = (const float*)d_in[10]; const float* b3a = (const float*)d_in[11];
    const float* W3b = (const float*)d_in[12]; const float* b3b = (const float*)d_in[13];

    int N = in_sizes[0] / 512;
    int E = in_sizes[1] / 2;
    const int* srcv = ei;
    const int* dstv = ei + E;
    int W = (N + NB - 1) / NB;            // bucket width (<= 512 required; 391 here)
    float recipW = 1.0f / (float)W;

    char* ws = (char*)d_ws;
    size_t off = 0;
    auto alloc = [&](size_t bytes) { void* p = ws + off; off = (off + bytes + 255) & ~(size_t)255; return p; };
    int*    offs     = (int*)   alloc((size_t)(N + 1) * 4);
    float*  dinv     = (float*) alloc((size_t)N * 4);
    int*    bcntpart = (int*)   alloc((size_t)CNTB * NB * 4);
    int*    bbase    = (int*)   alloc((NB + 1) * 4);
    int*    cursor256= (int*)   alloc(NB * 4);
    int*    csr      = (int*)   alloc((size_t)E * 4);
    ushort* Wt       = (ushort*)alloc(128 * 512 * 2);
    float*  bcat     = (float*) alloc(128 * 4);
    float*  W3s      = (float*) alloc(1280 * 4);
    float*  b3s      = (float*) alloc(40 * 4);
    ushort* HWp      = (ushort*)alloc((size_t)N * 128 * 2);   // [N][128] bf16
    ushort* xsp      = (ushort*)alloc((size_t)N * 32 * 2);    // [N][32] bf16
    float*  axs      = (float*) alloc((size_t)N * 32 * 4);

    // packed edge array aliases HWp (dead until gemm; E*4 <= N*128*2)
    int* epk = (int*)HWp;

    bucketcnt_kernel<<<CNTB, 256, 0, stream>>>(dstv, bcntpart, E, W, recipW);
    scan256_kernel<<<1, 256, 0, stream>>>(bcntpart, bbase, cursor256);
    bucket_kernel<<<(E + BKE - 1) / BKE, 256, 0, stream>>>(srcv, dstv, cursor256, epk, E, W, recipW);
    sortcsr_kernel<<<NB, 256, 0, stream>>>(epk, bbase, csr, offs, dinv, N, W, E);
    prep_kernel<<<256, 256, 0, stream>>>(W1a, W1b, W2a, W2b, b1a, b1b, b2a, b2b,
                                         W3a, W3b, b3a, b3b, Wt, bcat, W3s, b3s);
    gemm_mfma<<<(N + GBM - 1) / GBM, 256, 0, stream>>>(x, Wt, dinv, HWp, N);
    agg128<<<((size_t)N * 32 + 255) / 256, 256, 0, stream>>>(HWp, dinv, offs, csr, bcat, xsp, N);
    agg32<<<((size_t)N * 4 + 255) / 256, 256, 0, stream>>>(xsp, dinv, offs, csr, axs, N);
    final_kernel<<<(N + 255) / 256, 256, 0, stream>>>(axs, W3s, b3s, (float*)d_out, N);
}

// Round 12
// 341.255 us; speedup vs baseline: 1.2360x; 1.2360x over previous
//
#include <hip/hip_runtime.h>
#include <hip/hip_bf16.h>
#include <math.h>

typedef __attribute__((ext_vector_type(8))) short short8;
typedef __attribute__((ext_vector_type(4))) float f32x4;

__device__ inline ushort f2bf(float f) {
    uint u = __builtin_bit_cast(uint, f);
    u += 0x7fffu + ((u >> 16) & 1u);          // round-to-nearest-even
    return (ushort)(u >> 16);
}
__device__ inline float bf2f(ushort h) {
    return __builtin_bit_cast(float, (uint)h << 16);
}

// ================= CSR build: bucket counting-sort, zero global per-node atomics ==========

#define NB   256
#define CNTB 1024
#define BKE  2048
#define MAXBE 16384

__device__ inline int bucket_of(int d, int W, float recipW) {
    int g = (int)((float)d * recipW);
    if (g > NB - 1) g = NB - 1;
    while (d < g * W) --g;
    while (d >= (g + 1) * W) ++g;
    return g;
}

__global__ __launch_bounds__(256) void bucketcnt_kernel(const int* __restrict__ dst,
                                                        int* __restrict__ bcntpart,
                                                        int E, int W, float recipW) {
    __shared__ int hist[NB];
    int tid = threadIdx.x;
    hist[tid] = 0;
    __syncthreads();
    int per = (E + CNTB - 1) / CNTB;
    int e0 = blockIdx.x * per;
    int e1 = e0 + per; if (e1 > E) e1 = E;
    for (int e = e0 + tid; e < e1; e += 256)
        atomicAdd(&hist[bucket_of(dst[e], W, recipW)], 1);
    __syncthreads();
    bcntpart[blockIdx.x * NB + tid] = hist[tid];
}

__global__ __launch_bounds__(256) void scan256_kernel(const int* __restrict__ bcntpart,
                                                      int* __restrict__ bbase,
                                                      int* __restrict__ cursor256) {
    __shared__ int tot[NB];
    int b = threadIdx.x;
    int s = 0;
    for (int i = 0; i < CNTB; ++i) s += bcntpart[i * NB + b];
    int val = s;
    tot[b] = s;
    __syncthreads();
    for (int off = 1; off < NB; off <<= 1) {
        int t = (b >= off) ? tot[b - off] : 0;
        __syncthreads();
        tot[b] += t;
        __syncthreads();
    }
    int excl = tot[b] - val;
    bbase[b] = excl;
    cursor256[b] = excl;
    if (b == NB - 1) bbase[NB] = tot[NB - 1];
}

__global__ __launch_bounds__(256) void bucket_kernel(const int* __restrict__ src, const int* __restrict__ dst,
                                                     int* __restrict__ cursor256, int* __restrict__ epk,
                                                     int E, int W, float recipW) {
    __shared__ int hist[NB];
    __shared__ int base[NB];
    int tid = threadIdx.x;
    int e0 = blockIdx.x * BKE;
    int e1 = e0 + BKE; if (e1 > E) e1 = E;
    if (e0 >= E) return;
    hist[tid] = 0;
    __syncthreads();
    int myp[8], myg[8], myr[8];
    #pragma unroll
    for (int it = 0; it < 8; ++it) {
        int e = e0 + tid + it * 256;
        myg[it] = -1;
        if (e < e1) {
            int d = dst[e];
            int g = bucket_of(d, W, recipW);
            myp[it] = src[e] | ((d - g * W) << 17);
            myg[it] = g;
            myr[it] = atomicAdd(&hist[g], 1);
        }
    }
    __syncthreads();
    base[tid] = atomicAdd(&cursor256[tid], hist[tid]);
    __syncthreads();
    #pragma unroll
    for (int it = 0; it < 8; ++it)
        if (myg[it] >= 0)
            epk[base[myg[it]] + myr[it]] = myp[it];
}

__global__ __launch_bounds__(256) void sortcsr_kernel(const int* __restrict__ epk,
                                                      const int* __restrict__ bbase,
                                                      int* __restrict__ csr, int* __restrict__ offs,
                                                      float* __restrict__ dinv, int N, int W, int E) {
    __shared__ int lcnt[512];
    __shared__ int lofs[513];
    __shared__ int tmp[256];
    __shared__ int lcsr[MAXBE];
    int b = blockIdx.x;
    int lo = b * W;
    int nloc = N - lo; if (nloc > W) nloc = W; if (nloc < 0) nloc = 0;
    int eb = bbase[b], ee = bbase[b + 1];
    int tid = threadIdx.x;
    lcnt[2 * tid] = 0; lcnt[2 * tid + 1] = 0;
    __syncthreads();
    for (int e = eb + tid; e < ee; e += 256)
        atomicAdd(&lcnt[epk[e] >> 17], 1);
    __syncthreads();
    int a0 = lcnt[2 * tid], a1 = lcnt[2 * tid + 1];
    int psum = a0 + a1;
    tmp[tid] = psum;
    __syncthreads();
    for (int off = 1; off < 256; off <<= 1) {
        int t = (tid >= off) ? tmp[tid - off] : 0;
        __syncthreads();
        tmp[tid] += t;
        __syncthreads();
    }
    int excl = tmp[tid] - psum;
    lofs[2 * tid] = excl;
    lofs[2 * tid + 1] = excl + a0;
    lcnt[2 * tid] = excl;
    lcnt[2 * tid + 1] = excl + a0;
    if (tid == 255) lofs[512] = tmp[255];
    __syncthreads();
    for (int t = tid; t < nloc; t += 256) {
        offs[lo + t] = eb + lofs[t];
        int deg = lofs[t + 1] - lofs[t];
        dinv[lo + t] = rsqrtf((float)(deg + 1));
    }
    if (b == NB - 1 && tid == 0) offs[N] = E;
    for (int e = eb + tid; e < ee; e += 256) {
        int p = epk[e];
        int pos = atomicAdd(&lcnt[p >> 17], 1);
        int sv = p & 0x1FFFF;
        if (pos < MAXBE) lcsr[pos] = sv;
        else csr[eb + pos] = sv;
    }
    __syncthreads();
    int ne = ee - eb; if (ne > MAXBE) ne = MAXBE;
    for (int e = tid; e < ne; e += 256) csr[eb + e] = lcsr[e];
}

// ---------------- weight prep ----------------
// Wt is PRE-SWIZZLED for linear global_load_lds staging: within each row's 64-ushort
// k-group, 16B chunk at store-position c holds logical chunk c^(row&7).

__global__ __launch_bounds__(256) void prep_kernel(const float* __restrict__ W1a, const float* __restrict__ W1b,
                                                   const float* __restrict__ W2a, const float* __restrict__ W2b,
                                                   const float* __restrict__ b1a, const float* __restrict__ b1b,
                                                   const float* __restrict__ b2a, const float* __restrict__ b2b,
                                                   const float* __restrict__ W3a, const float* __restrict__ W3b,
                                                   const float* __restrict__ b3a, const float* __restrict__ b3b,
                                                   ushort* __restrict__ Wt, float* __restrict__ bcat,
                                                   float* __restrict__ W3s, float* __restrict__ b3s) {
    int idx = blockIdx.x * 256 + threadIdx.x;
    if (idx < 128 * 512) {
        int row = idx >> 9, kk = idx & 511;        // row = output col c (0..127)
        int cstore = (kk >> 3) & 7;
        int clog = cstore ^ (row & 7);
        int klog = (kk & ~63) | (clog << 3) | (kk & 7);
        const float* Wsrc = (row < 32) ? W1a : (row < 64) ? W1b : (row < 96) ? W2a : W2b;
        Wt[idx] = f2bf(Wsrc[klog * 32 + (row & 31)]);
    }
    if (idx < 1280) W3s[idx] = W3a[idx] + W3b[idx];
    if (idx < 128) {
        const float* b = (idx < 32) ? b1a : (idx < 64) ? b1b : (idx < 96) ? b2a : b2b;
        bcat[idx] = b[idx & 31];
    }
    if (idx < 40) b3s[idx] = b3a[idx] + b3b[idx];
}

// ---------------- MFMA GEMM: HWp[N][128] = bf16( (X@Wcat)[r][c] * dinv[r] ) ----------------
// m97-style: async global_load_lds (width 16) staging, single-buffered A(f32,16KB)+B(bf16,16KB),
// 2 barriers per K-step. Swizzle via pre-swizzled per-lane GLOBAL source addresses
// (A: chunk c^(row&15); B: baked into Wt), linear LDS dests. 32KB LDS -> 5 blocks/CU.

#define GBM 64

__global__ __launch_bounds__(256) void gemm_mfma(const float* __restrict__ X,
                                                 const ushort* __restrict__ Wt,
                                                 const float* __restrict__ dinv,
                                                 ushort* __restrict__ HWp, int N) {
    __shared__ float  Af[64 * 64];     // 16KB: pos (row, c) holds logical chunk c^(row&15)
    __shared__ ushort Bl[128 * 64];    // 16KB: pos (row, c) holds logical chunk c^(row&7)
    const int tid = threadIdx.x;
    const int lane = tid & 63;
    const int wave = tid >> 6;
    const int rQ = lane & 15, g = lane >> 4;
    const int rowBase = blockIdx.x * GBM;

    // Per-lane global source pointers (swizzle baked in). A: inst i covers chunks (i*4+wave)*64+lane.
    const float* agsrc[4];
    #pragma unroll
    for (int i = 0; i < 4; ++i) {
        int q = (i * 4 + wave) * 64 + lane;
        int row = q >> 4, c = q & 15;
        int rowg = rowBase + row; if (rowg > N - 1) rowg = N - 1;
        agsrc[i] = X + (size_t)rowg * 512 + ((c ^ (row & 15)) << 2);
    }
    const ushort* bgsrc[4];
    #pragma unroll
    for (int i = 0; i < 4; ++i) {
        int q = (i * 4 + wave) * 64 + lane;
        int row = q >> 3, c = q & 7;
        bgsrc[i] = Wt + (size_t)row * 512 + (c << 3);
    }

    f32x4 acc[4][2] = {};

#define STAGE(s)                                                              \
    {                                                                         \
        _Pragma("unroll")                                                     \
        for (int i = 0; i < 4; ++i)                                           \
            __builtin_amdgcn_global_load_lds(                                 \
                (const uint*)(agsrc[i] + (s) * 64),                           \
                (uint*)&Af[(i * 4 + wave) * 256], 16, 0, 0);                  \
        _Pragma("unroll")                                                     \
        for (int i = 0; i < 4; ++i)                                           \
            __builtin_amdgcn_global_load_lds(                                 \
                (const uint*)(bgsrc[i] + (s) * 64),                           \
                (uint*)&Bl[(i * 4 + wave) * 512], 16, 0, 0);                  \
    }

#define COMPUTE()                                                             \
    {                                                                         \
        short8 bfr[2][2];                                                     \
        _Pragma("unroll")                                                     \
        for (int ct2 = 0; ct2 < 2; ++ct2) {                                   \
            int brow = wave * 32 + ct2 * 16 + rQ;                             \
            _Pragma("unroll")                                                 \
            for (int sub = 0; sub < 2; ++sub)                                 \
                bfr[ct2][sub] = *(const short8*)(&Bl[brow * 64 + (((sub * 4 + g) ^ (brow & 7)) << 3)]); \
        }                                                                     \
        _Pragma("unroll")                                                     \
        for (int rt = 0; rt < 4; ++rt) {                                      \
            int arw = rt * 16 + rQ;                                           \
            _Pragma("unroll")                                                 \
            for (int sub = 0; sub < 2; ++sub) {                               \
                int c0 = (sub * 4 + g) * 2;                                   \
                float4 lo = *(const float4*)(&Af[arw * 64 + ((c0 ^ (arw & 15)) << 2)]);       \
                float4 hi = *(const float4*)(&Af[arw * 64 + (((c0 + 1) ^ (arw & 15)) << 2)]); \
                union { short8 s8; __hip_bfloat162 h[4]; } u;                 \
                u.h[0] = __float22bfloat162_rn({lo.x, lo.y});                 \
                u.h[1] = __float22bfloat162_rn({lo.z, lo.w});                 \
                u.h[2] = __float22bfloat162_rn({hi.x, hi.y});                 \
                u.h[3] = __float22bfloat162_rn({hi.z, hi.w});                 \
                _Pragma("unroll")                                             \
                for (int ct2 = 0; ct2 < 2; ++ct2)                             \
                    acc[rt][ct2] = __builtin_amdgcn_mfma_f32_16x16x32_bf16(   \
                        u.s8, bfr[ct2][sub], acc[rt][ct2], 0, 0, 0);          \
            }                                                                 \
        }                                                                     \
    }

    for (int s = 0; s < 8; ++s) {
        STAGE(s);
        __syncthreads();      // drains vmcnt -> tiles visible
        COMPUTE();
        __syncthreads();      // all waves done reading before next overwrite
    }

    // epilogue: scale by dinv[row], store bf16 (round-10 proven path)
    #pragma unroll
    for (int rt = 0; rt < 4; ++rt) {
        #pragma unroll
        for (int j = 0; j < 4; ++j) {
            int r = rowBase + rt * 16 + g * 4 + j;
            if (r < N) {
                float dv = dinv[r];
                #pragma unroll
                for (int ct2 = 0; ct2 < 2; ++ct2) {
                    int c = wave * 32 + ct2 * 16 + rQ;
                    HWp[(size_t)r * 128 + c] = f2bf(acc[rt][ct2][j] * dv);
                }
            }
        }
    }
#undef STAGE
#undef COMPUTE
}

// ---------------- aggregation 128 (bf16 gather, unroll-4 MLP) + fused relu/bias/block-sum ----------

__global__ __launch_bounds__(256) void agg128(const ushort* __restrict__ HWp, const float* __restrict__ dinv,
                                              const int* __restrict__ offs, const int* __restrict__ csr,
                                              const float* __restrict__ bcat, ushort* __restrict__ xsp, int N) {
    int t = blockIdx.x * 256 + threadIdx.x;
    int node = t >> 5, c = t & 31;      // lane c holds features 4c..4c+3
    if (node >= N) return;
    const ushort4* H = (const ushort4*)HWp;
    ushort4 h = H[(size_t)node * 32 + c];
    float a0 = bf2f(h.x), a1 = bf2f(h.y), a2 = bf2f(h.z), a3 = bf2f(h.w);
    int j = offs[node];
    int e1 = offs[node + 1];
    int jend = j + ((e1 - j) & ~3);
    for (; j < jend; j += 4) {
        int s0 = csr[j], s1 = csr[j + 1], s2 = csr[j + 2], s3 = csr[j + 3];
        ushort4 v0 = H[(size_t)s0 * 32 + c];
        ushort4 v1 = H[(size_t)s1 * 32 + c];
        ushort4 v2 = H[(size_t)s2 * 32 + c];
        ushort4 v3 = H[(size_t)s3 * 32 + c];
        a0 += bf2f(v0.x) + bf2f(v1.x) + bf2f(v2.x) + bf2f(v3.x);
        a1 += bf2f(v0.y) + bf2f(v1.y) + bf2f(v2.y) + bf2f(v3.y);
        a2 += bf2f(v0.z) + bf2f(v1.z) + bf2f(v2.z) + bf2f(v3.z);
        a3 += bf2f(v0.w) + bf2f(v1.w) + bf2f(v2.w) + bf2f(v3.w);
    }
    for (; j < e1; ++j) {
        int s = csr[j];
        ushort4 v = H[(size_t)s * 32 + c];
        a0 += bf2f(v.x); a1 += bf2f(v.y); a2 += bf2f(v.z); a3 += bf2f(v.w);
    }
    float di = dinv[node];
    float4 b = *(const float4*)(bcat + c * 4);
    float r0 = fmaxf(di * a0 + b.x, 0.f);
    float r1 = fmaxf(di * a1 + b.y, 0.f);
    float r2 = fmaxf(di * a2 + b.z, 0.f);
    float r3 = fmaxf(di * a3 + b.w, 0.f);
    r0 += __shfl_xor(r0, 8);  r1 += __shfl_xor(r1, 8);  r2 += __shfl_xor(r2, 8);  r3 += __shfl_xor(r3, 8);
    r0 += __shfl_xor(r0, 16); r1 += __shfl_xor(r1, 16); r2 += __shfl_xor(r2, 16); r3 += __shfl_xor(r3, 16);
    if ((c & 24) == 0) {
        ushort4 o;
        o.x = f2bf(r0 * di); o.y = f2bf(r1 * di); o.z = f2bf(r2 * di); o.w = f2bf(r3 * di);
        *(ushort4*)(xsp + (size_t)node * 32 + c * 4) = o;
    }
}

// ---------------- aggregation 32 (bf16 gather, unroll-4 MLP) -> axs f32 ----------------

__global__ __launch_bounds__(256) void agg32(const ushort* __restrict__ xsp, const float* __restrict__ dinv,
                                             const int* __restrict__ offs, const int* __restrict__ csr,
                                             float* __restrict__ axs, int N) {
    int t = blockIdx.x * 256 + threadIdx.x;
    int node = t >> 2, l = t & 3;
    if (node >= N) return;
    const short8* Xr = (const short8*)xsp;   // [N][4] chunks of 8 bf16
    short8 h = Xr[(size_t)node * 4 + l];
    float a[8];
    #pragma unroll
    for (int i = 0; i < 8; ++i) a[i] = bf2f((ushort)h[i]);
    int j = offs[node];
    int e1 = offs[node + 1];
    int jend = j + ((e1 - j) & ~3);
    for (; j < jend; j += 4) {
        int s0 = csr[j], s1 = csr[j + 1], s2 = csr[j + 2], s3 = csr[j + 3];
        short8 v0 = Xr[(size_t)s0 * 4 + l];
        short8 v1 = Xr[(size_t)s1 * 4 + l];
        short8 v2 = Xr[(size_t)s2 * 4 + l];
        short8 v3 = Xr[(size_t)s3 * 4 + l];
        #pragma unroll
        for (int i = 0; i < 8; ++i)
            a[i] += bf2f((ushort)v0[i]) + bf2f((ushort)v1[i]) + bf2f((ushort)v2[i]) + bf2f((ushort)v3[i]);
    }
    for (; j < e1; ++j) {
        int s = csr[j];
        short8 v = Xr[(size_t)s * 4 + l];
        #pragma unroll
        for (int i = 0; i < 8; ++i) a[i] += bf2f((ushort)v[i]);
    }
    float di = dinv[node];
    float4 o0 = make_float4(a[0] * di, a[1] * di, a[2] * di, a[3] * di);
    float4 o1 = make_float4(a[4] * di, a[5] * di, a[6] * di, a[7] * di);
    float* dst = axs + (size_t)node * 32 + l * 8;
    *(float4*)dst = o0;
    *(float4*)(dst + 4) = o1;
}

// ---------------- final: logits = axs @ W3s + b3s ; log_softmax ----------------

__global__ __launch_bounds__(256) void final_kernel(const float* __restrict__ axs, const float* __restrict__ W3s,
                                                    const float* __restrict__ b3s, float* __restrict__ out, int N) {
    __shared__ float w[32 * 40];
    __shared__ float b[40];
    int tid = threadIdx.x;
    for (int i = tid; i < 1280; i += 256) w[i] = W3s[i];
    if (tid < 40) b[tid] = b3s[tid];
    __syncthreads();
    int i = blockIdx.x * 256 + tid;
    if (i >= N) return;
    float a[32];
    #pragma unroll
    for (int q = 0; q < 8; ++q) {
        float4 v = *(const float4*)(axs + (size_t)i * 32 + q * 4);
        a[q * 4] = v.x; a[q * 4 + 1] = v.y; a[q * 4 + 2] = v.z; a[q * 4 + 3] = v.w;
    }
    float acc[40];
    #pragma unroll
    for (int c = 0; c < 40; ++c) acc[c] = b[c];
    #pragma unroll
    for (int k = 0; k < 32; ++k) {
        float av = a[k];
        #pragma unroll
        for (int c = 0; c < 40; ++c) acc[c] += av * w[k * 40 + c];
    }
    float m = acc[0];
    #pragma unroll
    for (int c = 1; c < 40; ++c) m = fmaxf(m, acc[c]);
    float sum = 0.f;
    #pragma unroll
    for (int c = 0; c < 40; ++c) sum += expf(acc[c] - m);
    float lg = m + logf(sum);
    #pragma unroll
    for (int c = 0; c < 40; ++c) out[(size_t)i * 40 + c] = acc[c] - lg;
}

// ---------------- launch ----------------

extern "C" void kernel_launch(void* const* d_in, const int* in_sizes, int n_in,
                              void* d_out, int out_size, void* d_ws, size_t ws_size,
                              hipStream_t stream) {
    const float* x   = (const float*)d_in[0];
    const int*   ei  = (const int*)d_in[1];
    const float* W1a = (const float*)d_in[2];  const float* b1a = (const float*)d_in[3];
    const float* W1b = (const float*)d_in[4];  const float* b1b = (const float*)d_in[5];
    const float* W2a = (const float*)d_in[6];  const float* b2a = (const float*)d_in[7];
    const float* W2b = (const float*)d_in[8];  const float* b2b = (const float*)d_in[9];
    const float* W3a = (const float*)d_in[10]; const float* b3a = (const float*)d_in[11];
    const float* W3b = (const float*)d_in[12]; const float* b3b = (const float*)d_in[13];

    int N = in_sizes[0] / 512;
    int E = in_sizes[1] / 2;
    const int* srcv = ei;
    const int* dstv = ei + E;
    int W = (N + NB - 1) / NB;
    float recipW = 1.0f / (float)W;

    char* ws = (char*)d_ws;
    size_t off = 0;
    auto alloc = [&](size_t bytes) { void* p = ws + off; off = (off + bytes + 255) & ~(size_t)255; return p; };
    int*    offs     = (int*)   alloc((size_t)(N + 1) * 4);
    float*  dinv     = (float*) alloc((size_t)N * 4);
    int*    bcntpart = (int*)   alloc((size_t)CNTB * NB * 4);
    int*    bbase    = (int*)   alloc((NB + 1) * 4);
    int*    cursor256= (int*)   alloc(NB * 4);
    int*    csr      = (int*)   alloc((size_t)E * 4);
    ushort* Wt       = (ushort*)alloc(128 * 512 * 2);
    float*  bcat     = (float*) alloc(128 * 4);
    float*  W3s      = (float*) alloc(1280 * 4);
    float*  b3s      = (float*) alloc(40 * 4);
    ushort* HWp      = (ushort*)alloc((size_t)N * 128 * 2);
    ushort* xsp      = (ushort*)alloc((size_t)N * 32 * 2);
    float*  axs      = (float*) alloc((size_t)N * 32 * 4);

    int* epk = (int*)HWp;   // aliases HWp (dead until gemm)

    bucketcnt_kernel<<<CNTB, 256, 0, stream>>>(dstv, bcntpart, E, W, recipW);
    scan256_kernel<<<1, 256, 0, stream>>>(bcntpart, bbase, cursor256);
    bucket_kernel<<<(E + BKE - 1) / BKE, 256, 0, stream>>>(srcv, dstv, cursor256, epk, E, W, recipW);
    sortcsr_kernel<<<NB, 256, 0, stream>>>(epk, bbase, csr, offs, dinv, N, W, E);
    prep_kernel<<<256, 256, 0, stream>>>(W1a, W1b, W2a, W2b, b1a, b1b, b2a, b2b,
                                         W3a, W3b, b3a, b3b, Wt, bcat, W3s, b3s);
    gemm_mfma<<<(N + GBM - 1) / GBM, 256, 0, stream>>>(x, Wt, dinv, HWp, N);
    agg128<<<((size_t)N * 32 + 255) / 256, 256, 0, stream>>>(HWp, dinv, offs, csr, bcat, xsp, N);
    agg32<<<((size_t)N * 4 + 255) / 256, 256, 0, stream>>>(xsp, dinv, offs, csr, axs, N);
    final_kernel<<<(N + 255) / 256, 256, 0, stream>>>(axs, W3s, b3s, (float*)d_out, N);
}

// Round 13
// 305.269 us; speedup vs baseline: 1.3817x; 1.1179x over previous
//
#include <hip/hip_runtime.h>
#include <hip/hip_bf16.h>
#include <math.h>

typedef __attribute__((ext_vector_type(8))) short short8;
typedef __attribute__((ext_vector_type(4))) float f32x4;

__device__ inline ushort f2bf(float f) {
    uint u = __builtin_bit_cast(uint, f);
    u += 0x7fffu + ((u >> 16) & 1u);          // round-to-nearest-even
    return (ushort)(u >> 16);
}
__device__ inline float bf2f(ushort h) {
    return __builtin_bit_cast(float, (uint)h << 16);
}

// ================= CSR build: fixed-capacity bucket counting-sort =================
// 256 node-range buckets of width W=ceil(N/256); epk region b = [b*CAP, b*CAP+CAP).
// Edge packed as src | ((d - b*W) << 17). CAP = 16384 ≈ mean 12.5K + 35 sigma.

#define NB   256
#define BKE  2048
#define CAP  16384
#define MAXBE 16384

__device__ inline int bucket_of(int d, int W, float recipW) {
    int g = (int)((float)d * recipW);
    if (g > NB - 1) g = NB - 1;
    while (d < g * W) --g;
    while (d >= (g + 1) * W) ++g;
    return g;
}

__global__ void initcur_kernel(int* __restrict__ cursor256) {
    cursor256[threadIdx.x] = threadIdx.x * CAP;
}

__global__ __launch_bounds__(256) void bucket_kernel(const int* __restrict__ src, const int* __restrict__ dst,
                                                     int* __restrict__ cursor256, int* __restrict__ epk,
                                                     int E, int W, float recipW) {
    __shared__ int hist[NB];
    __shared__ int base[NB];
    int tid = threadIdx.x;
    int e0 = blockIdx.x * BKE;
    int e1 = e0 + BKE; if (e1 > E) e1 = E;
    if (e0 >= E) return;
    hist[tid] = 0;
    __syncthreads();
    int myp[8], myg[8], myr[8];
    #pragma unroll
    for (int it = 0; it < 8; ++it) {
        int e = e0 + tid + it * 256;
        myg[it] = -1;
        if (e < e1) {
            int d = dst[e];
            int g = bucket_of(d, W, recipW);
            myp[it] = src[e] | ((d - g * W) << 17);
            myg[it] = g;
            myr[it] = atomicAdd(&hist[g], 1);
        }
    }
    __syncthreads();
    base[tid] = atomicAdd(&cursor256[tid], hist[tid]);
    __syncthreads();
    #pragma unroll
    for (int it = 0; it < 8; ++it)
        if (myg[it] >= 0)
            epk[base[myg[it]] + myr[it]] = myp[it];
}

// bbase[b] = global csr offset of bucket b (exclusive scan of per-bucket counts)
__global__ void scanpost_kernel(const int* __restrict__ cursor256, int* __restrict__ bbase) {
    __shared__ int tot[NB];
    int b = threadIdx.x;
    int cnt = cursor256[b] - b * CAP;
    tot[b] = cnt;
    __syncthreads();
    for (int off = 1; off < NB; off <<= 1) {
        int t = (b >= off) ? tot[b - off] : 0;
        __syncthreads();
        tot[b] += t;
        __syncthreads();
    }
    bbase[b] = tot[b] - cnt;
    if (b == NB - 1) bbase[NB] = tot[NB - 1];
}

// one block per bucket: LDS histogram -> scan -> offs/dinv out -> LDS counting-scatter -> csr
__global__ __launch_bounds__(256) void sortcsr_kernel(const int* __restrict__ epk,
                                                      const int* __restrict__ bbase,
                                                      int* __restrict__ csr, int* __restrict__ offs,
                                                      float* __restrict__ dinv, int N, int W, int E) {
    __shared__ int lcnt[512];
    __shared__ int lofs[513];
    __shared__ int tmp[256];
    __shared__ int lcsr[MAXBE];
    int b = blockIdx.x;
    int lo = b * W;
    int nloc = N - lo; if (nloc > W) nloc = W; if (nloc < 0) nloc = 0;
    int gbase = bbase[b];
    int cnt = bbase[b + 1] - gbase;
    int ebk = b * CAP;                 // epk region start
    int tid = threadIdx.x;
    lcnt[2 * tid] = 0; lcnt[2 * tid + 1] = 0;
    __syncthreads();
    for (int e = tid; e < cnt; e += 256)
        atomicAdd(&lcnt[epk[ebk + e] >> 17], 1);
    __syncthreads();
    int a0 = lcnt[2 * tid], a1 = lcnt[2 * tid + 1];
    int psum = a0 + a1;
    tmp[tid] = psum;
    __syncthreads();
    for (int off = 1; off < 256; off <<= 1) {
        int t = (tid >= off) ? tmp[tid - off] : 0;
        __syncthreads();
        tmp[tid] += t;
        __syncthreads();
    }
    int excl = tmp[tid] - psum;
    lofs[2 * tid] = excl;
    lofs[2 * tid + 1] = excl + a0;
    lcnt[2 * tid] = excl;
    lcnt[2 * tid + 1] = excl + a0;
    if (tid == 255) lofs[512] = tmp[255];
    __syncthreads();
    for (int t = tid; t < nloc; t += 256) {
        offs[lo + t] = gbase + lofs[t];
        int deg = lofs[t + 1] - lofs[t];
        dinv[lo + t] = rsqrtf((float)(deg + 1));
    }
    if (b == NB - 1 && tid == 0) offs[N] = E;
    for (int e = tid; e < cnt; e += 256) {
        int p = epk[ebk + e];
        int pos = atomicAdd(&lcnt[p >> 17], 1);
        int sv = p & 0x1FFFF;
        if (pos < MAXBE) lcsr[pos] = sv;
        else csr[gbase + pos] = sv;    // unreachable unless bucket > CAP
    }
    __syncthreads();
    int ne = cnt; if (ne > MAXBE) ne = MAXBE;
    for (int e = tid; e < ne; e += 256) csr[gbase + e] = lcsr[e];
}

// ---------------- weight prep ----------------
// Wt is PRE-SWIZZLED for linear global_load_lds staging: within each row's 64-ushort
// k-group, 16B chunk at store-position c holds logical chunk c^(row&7).

__global__ __launch_bounds__(256) void prep_kernel(const float* __restrict__ W1a, const float* __restrict__ W1b,
                                                   const float* __restrict__ W2a, const float* __restrict__ W2b,
                                                   const float* __restrict__ b1a, const float* __restrict__ b1b,
                                                   const float* __restrict__ b2a, const float* __restrict__ b2b,
                                                   const float* __restrict__ W3a, const float* __restrict__ W3b,
                                                   const float* __restrict__ b3a, const float* __restrict__ b3b,
                                                   ushort* __restrict__ Wt, float* __restrict__ bcat,
                                                   float* __restrict__ W3s, float* __restrict__ b3s) {
    int idx = blockIdx.x * 256 + threadIdx.x;
    if (idx < 128 * 512) {
        int row = idx >> 9, kk = idx & 511;        // row = output col c (0..127)
        int cstore = (kk >> 3) & 7;
        int clog = cstore ^ (row & 7);
        int klog = (kk & ~63) | (clog << 3) | (kk & 7);
        const float* Wsrc = (row < 32) ? W1a : (row < 64) ? W1b : (row < 96) ? W2a : W2b;
        Wt[idx] = f2bf(Wsrc[klog * 32 + (row & 31)]);
    }
    if (idx < 1280) W3s[idx] = W3a[idx] + W3b[idx];
    if (idx < 128) {
        const float* b = (idx < 32) ? b1a : (idx < 64) ? b1b : (idx < 96) ? b2a : b2b;
        bcat[idx] = b[idx & 31];
    }
    if (idx < 40) b3s[idx] = b3a[idx] + b3b[idx];
}

// ---------------- MFMA GEMM: HWp[N][128] = bf16( (X@Wcat)[r][c] * dinv[r] ) ----------------
// async global_load_lds staging (width 16), A f32 + B bf16 single-buffered, 32KB LDS.

#define GBM 64

__global__ __launch_bounds__(256) void gemm_mfma(const float* __restrict__ X,
                                                 const ushort* __restrict__ Wt,
                                                 const float* __restrict__ dinv,
                                                 ushort* __restrict__ HWp, int N) {
    __shared__ float  Af[64 * 64];     // pos (row, c) holds logical chunk c^(row&15)
    __shared__ ushort Bl[128 * 64];    // pos (row, c) holds logical chunk c^(row&7)
    const int tid = threadIdx.x;
    const int lane = tid & 63;
    const int wave = tid >> 6;
    const int rQ = lane & 15, g = lane >> 4;
    const int rowBase = blockIdx.x * GBM;

    const float* agsrc[4];
    #pragma unroll
    for (int i = 0; i < 4; ++i) {
        int q = (i * 4 + wave) * 64 + lane;
        int row = q >> 4, c = q & 15;
        int rowg = rowBase + row; if (rowg > N - 1) rowg = N - 1;
        agsrc[i] = X + (size_t)rowg * 512 + ((c ^ (row & 15)) << 2);
    }
    const ushort* bgsrc[4];
    #pragma unroll
    for (int i = 0; i < 4; ++i) {
        int q = (i * 4 + wave) * 64 + lane;
        int row = q >> 3, c = q & 7;
        bgsrc[i] = Wt + (size_t)row * 512 + (c << 3);
    }

    f32x4 acc[4][2] = {};

#define STAGE(s)                                                              \
    {                                                                         \
        _Pragma("unroll")                                                     \
        for (int i = 0; i < 4; ++i)                                           \
            __builtin_amdgcn_global_load_lds(                                 \
                (const uint*)(agsrc[i] + (s) * 64),                           \
                (uint*)&Af[(i * 4 + wave) * 256], 16, 0, 0);                  \
        _Pragma("unroll")                                                     \
        for (int i = 0; i < 4; ++i)                                           \
            __builtin_amdgcn_global_load_lds(                                 \
                (const uint*)(bgsrc[i] + (s) * 64),                           \
                (uint*)&Bl[(i * 4 + wave) * 512], 16, 0, 0);                  \
    }

#define COMPUTE()                                                             \
    {                                                                         \
        short8 bfr[2][2];                                                     \
        _Pragma("unroll")                                                     \
        for (int ct2 = 0; ct2 < 2; ++ct2) {                                   \
            int brow = wave * 32 + ct2 * 16 + rQ;                             \
            _Pragma("unroll")                                                 \
            for (int sub = 0; sub < 2; ++sub)                                 \
                bfr[ct2][sub] = *(const short8*)(&Bl[brow * 64 + (((sub * 4 + g) ^ (brow & 7)) << 3)]); \
        }                                                                     \
        _Pragma("unroll")                                                     \
        for (int rt = 0; rt < 4; ++rt) {                                      \
            int arw = rt * 16 + rQ;                                           \
            _Pragma("unroll")                                                 \
            for (int sub = 0; sub < 2; ++sub) {                               \
                int c0 = (sub * 4 + g) * 2;                                   \
                float4 lo = *(const float4*)(&Af[arw * 64 + ((c0 ^ (arw & 15)) << 2)]);       \
                float4 hi = *(const float4*)(&Af[arw * 64 + (((c0 + 1) ^ (arw & 15)) << 2)]); \
                union { short8 s8; __hip_bfloat162 h[4]; } u;                 \
                u.h[0] = __float22bfloat162_rn({lo.x, lo.y});                 \
                u.h[1] = __float22bfloat162_rn({lo.z, lo.w});                 \
                u.h[2] = __float22bfloat162_rn({hi.x, hi.y});                 \
                u.h[3] = __float22bfloat162_rn({hi.z, hi.w});                 \
                _Pragma("unroll")                                             \
                for (int ct2 = 0; ct2 < 2; ++ct2)                             \
                    acc[rt][ct2] = __builtin_amdgcn_mfma_f32_16x16x32_bf16(   \
                        u.s8, bfr[ct2][sub], acc[rt][ct2], 0, 0, 0);          \
            }                                                                 \
        }                                                                     \
    }

    for (int s = 0; s < 8; ++s) {
        STAGE(s);
        __syncthreads();
        COMPUTE();
        __syncthreads();
    }

    #pragma unroll
    for (int rt = 0; rt < 4; ++rt) {
        #pragma unroll
        for (int j = 0; j < 4; ++j) {
            int r = rowBase + rt * 16 + g * 4 + j;
            if (r < N) {
                float dv = dinv[r];
                #pragma unroll
                for (int ct2 = 0; ct2 < 2; ++ct2) {
                    int c = wave * 32 + ct2 * 16 + rQ;
                    HWp[(size_t)r * 128 + c] = f2bf(acc[rt][ct2][j] * dv);
                }
            }
        }
    }
#undef STAGE
#undef COMPUTE
}

// ---------------- aggregation 128: 16 lanes/node x 16B, unroll 8 ----------------
// HWp pre-scaled by dinv[src]. xsp[node] = bf16( dinv*sum_blk relu(dinv*agg + bcat) )

__global__ __launch_bounds__(256) void agg128(const ushort* __restrict__ HWp, const float* __restrict__ dinv,
                                              const int* __restrict__ offs, const int* __restrict__ csr,
                                              const float* __restrict__ bcat, ushort* __restrict__ xsp, int N) {
    int t = blockIdx.x * 256 + threadIdx.x;
    int node = t >> 4, c = t & 15;          // lane c holds feats 8c..8c+7
    if (node >= N) return;
    const short8* H = (const short8*)HWp;   // row = 16 chunks of 8 bf16
    short8 h = H[(size_t)node * 16 + c];
    float a[8];
    #pragma unroll
    for (int i = 0; i < 8; ++i) a[i] = bf2f((ushort)h[i]);
    int j = offs[node];
    int e1 = offs[node + 1];
    int jend = j + ((e1 - j) & ~7);
    for (; j < jend; j += 8) {
        int s[8];
        #pragma unroll
        for (int q = 0; q < 8; ++q) s[q] = csr[j + q];
        short8 v[8];
        #pragma unroll
        for (int q = 0; q < 8; ++q) v[q] = H[(size_t)s[q] * 16 + c];
        #pragma unroll
        for (int q = 0; q < 8; ++q)
            #pragma unroll
            for (int i = 0; i < 8; ++i) a[i] += bf2f((ushort)v[q][i]);
    }
    for (; j < e1; ++j) {
        short8 v = H[(size_t)csr[j] * 16 + c];
        #pragma unroll
        for (int i = 0; i < 8; ++i) a[i] += bf2f((ushort)v[i]);
    }
    float di = dinv[node];
    float4 b0 = *(const float4*)(bcat + c * 8);
    float4 b1 = *(const float4*)(bcat + c * 8 + 4);
    float bb[8] = {b0.x, b0.y, b0.z, b0.w, b1.x, b1.y, b1.z, b1.w};
    float r[8];
    #pragma unroll
    for (int i = 0; i < 8; ++i) r[i] = fmaxf(di * a[i] + bb[i], 0.f);
    #pragma unroll
    for (int i = 0; i < 8; ++i) { r[i] += __shfl_xor(r[i], 4); r[i] += __shfl_xor(r[i], 8); }
    if ((c & 12) == 0) {                    // lanes c=0..3 hold feats 8c..8c+7 block-sums
        union { short8 s8; ushort us[8]; } o;
        #pragma unroll
        for (int i = 0; i < 8; ++i) o.us[i] = f2bf(r[i] * di);
        *(short8*)(xsp + (size_t)node * 32 + c * 8) = o.s8;
    }
}

// ---------------- aggregation 32: 4 lanes/node x 16B, unroll 8 -> axs f32 ----------------

__global__ __launch_bounds__(256) void agg32(const ushort* __restrict__ xsp, const float* __restrict__ dinv,
                                             const int* __restrict__ offs, const int* __restrict__ csr,
                                             float* __restrict__ axs, int N) {
    int t = blockIdx.x * 256 + threadIdx.x;
    int node = t >> 2, l = t & 3;
    if (node >= N) return;
    const short8* Xr = (const short8*)xsp;   // [N][4] chunks of 8 bf16
    short8 h = Xr[(size_t)node * 4 + l];
    float a[8];
    #pragma unroll
    for (int i = 0; i < 8; ++i) a[i] = bf2f((ushort)h[i]);
    int j = offs[node];
    int e1 = offs[node + 1];
    int jend = j + ((e1 - j) & ~7);
    for (; j < jend; j += 8) {
        int s[8];
        #pragma unroll
        for (int q = 0; q < 8; ++q) s[q] = csr[j + q];
        short8 v[8];
        #pragma unroll
        for (int q = 0; q < 8; ++q) v[q] = Xr[(size_t)s[q] * 4 + l];
        #pragma unroll
        for (int q = 0; q < 8; ++q)
            #pragma unroll
            for (int i = 0; i < 8; ++i) a[i] += bf2f((ushort)v[q][i]);
    }
    for (; j < e1; ++j) {
        short8 v = Xr[(size_t)csr[j] * 4 + l];
        #pragma unroll
        for (int i = 0; i < 8; ++i) a[i] += bf2f((ushort)v[i]);
    }
    float di = dinv[node];
    float4 o0 = make_float4(a[0] * di, a[1] * di, a[2] * di, a[3] * di);
    float4 o1 = make_float4(a[4] * di, a[5] * di, a[6] * di, a[7] * di);
    float* dst = axs + (size_t)node * 32 + l * 8;
    *(float4*)dst = o0;
    *(float4*)(dst + 4) = o1;
}

// ---------------- final: logits = axs @ W3s + b3s ; log_softmax ----------------

__global__ __launch_bounds__(256) void final_kernel(const float* __restrict__ axs, const float* __restrict__ W3s,
                                                    const float* __restrict__ b3s, float* __restrict__ out, int N) {
    __shared__ float w[32 * 40];
    __shared__ float b[40];
    int tid = threadIdx.x;
    for (int i = tid; i < 1280; i += 256) w[i] = W3s[i];
    if (tid < 40) b[tid] = b3s[tid];
    __syncthreads();
    int i = blockIdx.x * 256 + tid;
    if (i >= N) return;
    float a[32];
    #pragma unroll
    for (int q = 0; q < 8; ++q) {
        float4 v = *(const float4*)(axs + (size_t)i * 32 + q * 4);
        a[q * 4] = v.x; a[q * 4 + 1] = v.y; a[q * 4 + 2] = v.z; a[q * 4 + 3] = v.w;
    }
    float acc[40];
    #pragma unroll
    for (int c = 0; c < 40; ++c) acc[c] = b[c];
    #pragma unroll
    for (int k = 0; k < 32; ++k) {
        float av = a[k];
        #pragma unroll
        for (int c = 0; c < 40; ++c) acc[c] += av * w[k * 40 + c];
    }
    float m = acc[0];
    #pragma unroll
    for (int c = 1; c < 40; ++c) m = fmaxf(m, acc[c]);
    float sum = 0.f;
    #pragma unroll
    for (int c = 0; c < 40; ++c) sum += expf(acc[c] - m);
    float lg = m + logf(sum);
    #pragma unroll
    for (int c = 0; c < 40; ++c) out[(size_t)i * 40 + c] = acc[c] - lg;
}

// ---------------- launch ----------------

extern "C" void kernel_launch(void* const* d_in, const int* in_sizes, int n_in,
                              void* d_out, int out_size, void* d_ws, size_t ws_size,
                              hipStream_t stream) {
    const float* x   = (const float*)d_in[0];
    const int*   ei  = (const int*)d_in[1];
    const float* W1a = (const float*)d_in[2];  const float* b1a = (const float*)d_in[3];
    const float* W1b = (const float*)d_in[4];  const float* b1b = (const float*)d_in[5];
    const float* W2a = (const float*)d_in[6];  const float* b2a = (const float*)d_in[7];
    const float* W2b = (const float*)d_in[8];  const float* b2b = (const float*)d_in[9];
    const float* W3a = (const float*)d_in[10]; const float* b3a = (const float*)d_in[11];
    const float* W3b = (const float*)d_in[12]; const float* b3b = (const float*)d_in[13];

    int N = in_sizes[0] / 512;
    int E = in_sizes[1] / 2;
    const int* srcv = ei;
    const int* dstv = ei + E;
    int W = (N + NB - 1) / NB;
    float recipW = 1.0f / (float)W;

    char* ws = (char*)d_ws;
    size_t off = 0;
    auto alloc = [&](size_t bytes) { void* p = ws + off; off = (off + bytes + 255) & ~(size_t)255; return p; };
    int*    offs     = (int*)   alloc((size_t)(N + 1) * 4);
    float*  dinv     = (float*) alloc((size_t)N * 4);
    int*    bbase    = (int*)   alloc((NB + 1) * 4);
    int*    cursor256= (int*)   alloc(NB * 4);
    int*    csr      = (int*)   alloc((size_t)E * 4);
    ushort* Wt       = (ushort*)alloc(128 * 512 * 2);
    float*  bcat     = (float*) alloc(128 * 4);
    float*  W3s      = (float*) alloc(1280 * 4);
    float*  b3s      = (float*) alloc(40 * 4);
    ushort* HWp      = (ushort*)alloc((size_t)N * 128 * 2);
    ushort* xsp      = (ushort*)alloc((size_t)N * 32 * 2);
    float*  axs      = (float*) alloc((size_t)N * 32 * 4);

    int* epk = (int*)HWp;   // 256*CAP*4 = 16.8MB, aliases HWp (dead until gemm)

    initcur_kernel<<<1, 256, 0, stream>>>(cursor256);
    bucket_kernel<<<(E + BKE - 1) / BKE, 256, 0, stream>>>(srcv, dstv, cursor256, epk, E, W, recipW);
    scanpost_kernel<<<1, 256, 0, stream>>>(cursor256, bbase);
    sortcsr_kernel<<<NB, 256, 0, stream>>>(epk, bbase, csr, offs, dinv, N, W, E);
    prep_kernel<<<256, 256, 0, stream>>>(W1a, W1b, W2a, W2b, b1a, b1b, b2a, b2b,
                                         W3a, W3b, b3a, b3b, Wt, bcat, W3s, b3s);
    gemm_mfma<<<(N + GBM - 1) / GBM, 256, 0, stream>>>(x, Wt, dinv, HWp, N);
    agg128<<<((size_t)N * 16 + 255) / 256, 256, 0, stream>>>(HWp, dinv, offs, csr, bcat, xsp, N);
    agg32<<<((size_t)N * 4 + 255) / 256, 256, 0, stream>>>(xsp, dinv, offs, csr, axs, N);
    final_kernel<<<(N + 255) / 256, 256, 0, stream>>>(axs, W3s, b3s, (float*)d_out, N);
}